// Round 11
// baseline (259.073 us; speedup 1.0000x reference)
//
#include <hip/hip_runtime.h>
#include <hip/hip_bf16.h>
#include <stdint.h>

typedef __bf16 bf16;
typedef __bf16 bf16x8 __attribute__((ext_vector_type(8)));
typedef float floatx4 __attribute__((ext_vector_type(4)));

typedef const __attribute__((address_space(1))) uint32_t glb_u32;
typedef __attribute__((address_space(3))) uint32_t lds_u32;

__device__ __forceinline__ void cp16(void* lds, const void* gp) {
    __builtin_amdgcn_global_load_lds((glb_u32*)gp, (lds_u32*)lds, 16, 0, 0);
}

#define MFMA16(a, b, c) __builtin_amdgcn_mfma_f32_16x16x32_bf16((a), (b), (c), 0, 0, 0)
#define SCALE_ 0.125f

// ---------------------------------------------------------------------------
// K0: fused cvt + prep + xsum stage A.
// blocks [0,4096): fp32->bf16 cvt of x (hi+lo), w_qkv, w_out
// blocks [4096,4352): whl hi/lo rows of mean-head Wq
// blocks [4352,4416): per-batch column-sum partials of x (stage A)
// ---------------------------------------------------------------------------
__global__ __launch_bounds__(256) void k_cvt_prep(
    const float* __restrict__ x, const float* __restrict__ wq,
    const float* __restrict__ wo, bf16* __restrict__ xb,
    bf16* __restrict__ xl, bf16* __restrict__ wqb, bf16* __restrict__ wob,
    bf16* __restrict__ whl, float* __restrict__ partial) {
    if (blockIdx.x < 4096) {
        size_t i8 = ((size_t)blockIdx.x * 256 + threadIdx.x) * 8;
        const float* src; bf16* dst; size_t off; bool isx = false;
        if (i8 < 4194304)      { src = x;  dst = xb;  off = i8; isx = true; }
        else if (i8 < 7340032) { src = wq; dst = wqb; off = i8 - 4194304; }
        else                   { src = wo; dst = wob; off = i8 - 7340032; }
        float4 a = *(const float4*)(src + off);
        float4 b = *(const float4*)(src + off + 4);
        union { bf16 h[8]; uint4 u; } hi, lo;
        hi.h[0] = (bf16)a.x; hi.h[1] = (bf16)a.y; hi.h[2] = (bf16)a.z; hi.h[3] = (bf16)a.w;
        hi.h[4] = (bf16)b.x; hi.h[5] = (bf16)b.y; hi.h[6] = (bf16)b.z; hi.h[7] = (bf16)b.w;
        *(uint4*)(dst + off) = hi.u;
        if (isx) {
            lo.h[0] = (bf16)(a.x - (float)hi.h[0]);
            lo.h[1] = (bf16)(a.y - (float)hi.h[1]);
            lo.h[2] = (bf16)(a.z - (float)hi.h[2]);
            lo.h[3] = (bf16)(a.w - (float)hi.h[3]);
            lo.h[4] = (bf16)(b.x - (float)hi.h[4]);
            lo.h[5] = (bf16)(b.y - (float)hi.h[5]);
            lo.h[6] = (bf16)(b.z - (float)hi.h[6]);
            lo.h[7] = (bf16)(b.w - (float)hi.h[7]);
            *(uint4*)(xl + off) = lo.u;
        }
    } else if (blockIdx.x < 4352) {
        int t = (blockIdx.x - 4096) * 256 + threadIdx.x;   // 0..65535
        int k = t & 1023, d = t >> 10;
        float s = 0.f;
        #pragma unroll
        for (int h = 0; h < 16; ++h) s += wq[(size_t)(h * 64 + d) * 1024 + k];
        s *= (1.f / 16.f);
        bf16 hi = (bf16)s;
        whl[(size_t)d * 1024 + k] = hi;
        whl[(size_t)(64 + d) * 1024 + k] = (bf16)(s - (float)hi);
    } else {
        const int g = blockIdx.x - 4352;   // 0..63
        const int b = g >> 4, rg = g & 15;
        const size_t base = ((size_t)b * 1024 + rg * 64) * 1024;
        const int c = threadIdx.x * 4;
        float4 acc = {0.f, 0.f, 0.f, 0.f};
        for (int i = 0; i < 64; ++i) {
            float4 xv = *(const float4*)(x + base + (size_t)i * 1024 + c);
            acc.x += xv.x; acc.y += xv.y; acc.z += xv.z; acc.w += xv.w;
        }
        *(float4*)(partial + (size_t)g * 1024 + c) = acc;
    }
}

// ---------------------------------------------------------------------------
// K1: fused score pipeline.
// blocks [0,32): qm GEMM (hi/lo-split MFMA) -> LDS -> LN/GELU/score in-block.
// blocks [32,48): xsum stage B -> xsumhl bf16 hi/lo rows.
// Score math is bitwise-identical to the round-10 passing kernel.
// ---------------------------------------------------------------------------
__global__ __launch_bounds__(256) void k_score_gemm(
    const bf16* __restrict__ xh, const bf16* __restrict__ xl,
    const bf16* __restrict__ whl, const float* __restrict__ partial,
    bf16* __restrict__ xsumhl, const float* __restrict__ lng,
    const float* __restrict__ lnb, const float* __restrict__ w1f,
    const float* __restrict__ b1f, const float* __restrict__ w2f,
    const float* __restrict__ b2f, float* __restrict__ scores) {
    if (blockIdx.x >= 32) {
        const int o = (blockIdx.x - 32) * 256 + threadIdx.x;   // 0..4095
        const int b = o >> 10, k = o & 1023;
        float s = 0.f;
        #pragma unroll
        for (int g = 0; g < 16; ++g) s += partial[(size_t)(b * 16 + g) * 1024 + k];
        bf16 hi = (bf16)s;
        xsumhl[(size_t)b * 1024 + k] = hi;
        xsumhl[(size_t)(4 + b) * 1024 + k] = (bf16)(s - (float)hi);
        return;
    }
    __shared__ bf16 Ah[128 * 32];
    __shared__ bf16 Al[128 * 32];
    __shared__ bf16 Bs[128 * 32];
    __shared__ float Qm[128][64];
    __shared__ float Hs[4][64];
    __shared__ float hh[4][16];
    const int t = threadIdx.x;
    const int lane = t & 63;
    const int w = t >> 6;
    const int m0 = blockIdx.x * 128;
    const int srow = t >> 2;
    const int scol = (t & 3) * 8;
    const int fr = lane & 15;
    const int kc = (lane >> 4) * 8;
    const int wm0 = w * 32;

    floatx4 zero4 = {0.f, 0.f, 0.f, 0.f};
    floatx4 acc[2][4];
    #pragma unroll
    for (int i = 0; i < 2; ++i)
        #pragma unroll
        for (int j = 0; j < 4; ++j) acc[i][j] = zero4;

    for (int k0 = 0; k0 < 1024; k0 += 32) {
        __syncthreads();
        cp16(Ah + t * 8,        xh + (size_t)(m0 + srow) * 1024 + k0 + scol);
        cp16(Ah + t * 8 + 2048, xh + (size_t)(m0 + srow + 64) * 1024 + k0 + scol);
        cp16(Al + t * 8,        xl + (size_t)(m0 + srow) * 1024 + k0 + scol);
        cp16(Al + t * 8 + 2048, xl + (size_t)(m0 + srow + 64) * 1024 + k0 + scol);
        cp16(Bs + t * 8,        whl + (size_t)srow * 1024 + k0 + scol);
        cp16(Bs + t * 8 + 2048, whl + (size_t)(srow + 64) * 1024 + k0 + scol);
        __syncthreads();
        bf16x8 ah[2], al[2], bh[4], bl[4];
        #pragma unroll
        for (int mi = 0; mi < 2; ++mi) {
            ah[mi] = *(const bf16x8*)&Ah[(wm0 + mi * 16 + fr) * 32 + kc];
            al[mi] = *(const bf16x8*)&Al[(wm0 + mi * 16 + fr) * 32 + kc];
        }
        #pragma unroll
        for (int ni = 0; ni < 4; ++ni) {
            bh[ni] = *(const bf16x8*)&Bs[(ni * 16 + fr) * 32 + kc];
            bl[ni] = *(const bf16x8*)&Bs[(64 + ni * 16 + fr) * 32 + kc];
        }
        #pragma unroll
        for (int mi = 0; mi < 2; ++mi)
            #pragma unroll
            for (int ni = 0; ni < 4; ++ni) {
                acc[mi][ni] = MFMA16(ah[mi], bh[ni], acc[mi][ni]);
                acc[mi][ni] = MFMA16(ah[mi], bl[ni], acc[mi][ni]);
                acc[mi][ni] = MFMA16(al[mi], bh[ni], acc[mi][ni]);
            }
    }

    const int rowb = (lane >> 4) * 4;
    #pragma unroll
    for (int mi = 0; mi < 2; ++mi)
        #pragma unroll
        for (int ni = 0; ni < 4; ++ni)
            #pragma unroll
            for (int r = 0; r < 4; ++r)
                Qm[wm0 + mi * 16 + rowb + r][ni * 16 + fr] = acc[mi][ni][r];
    __syncthreads();

    // fused tail: wave w processes rows w*32 .. w*32+31 (same per-row math
    // and reduction order as the standalone k_score_tail -> bitwise equal).
    for (int i = 0; i < 32; ++i) {
        const int row = w * 32 + i;
        float qm = Qm[row][lane];
        float s = qm;
        #pragma unroll
        for (int off = 32; off > 0; off >>= 1) s += __shfl_xor(s, off);
        float mu = s * (1.f / 64.f);
        float dx = qm - mu;
        float v2 = dx * dx;
        #pragma unroll
        for (int off = 32; off > 0; off >>= 1) v2 += __shfl_xor(v2, off);
        float var = v2 * (1.f / 64.f);
        float H = dx * (1.0f / sqrtf(var + 1e-5f)) * lng[lane] + lnb[lane];
        Hs[w][lane] = H;
        if (lane < 16) {
            float a = b1f[lane];
            #pragma unroll
            for (int d = 0; d < 64; ++d) a += Hs[w][d] * w1f[lane * 64 + d];
            hh[w][lane] = 0.5f * a * (1.0f + erff(a * 0.70710678118654752f));
        }
        if (lane == 0) {
            float sc = b2f[0];
            #pragma unroll
            for (int p = 0; p < 16; ++p) sc += hh[w][p] * w2f[p];
            scores[m0 + row] = sc;
        }
    }
}

// ---------------------------------------------------------------------------
// K2: top-256 radix select (unchanged).
// ---------------------------------------------------------------------------
__global__ __launch_bounds__(256) void k_topk(const float* __restrict__ scores,
                                              float* __restrict__ gate,
                                              int* __restrict__ idx,
                                              float* __restrict__ gsel) {
    const int w = threadIdx.x >> 6, lane = threadIdx.x & 63;   // w = batch
    const float* sc = scores + w * 1024;
    float s[16];
    uint32_t key[16];
    #pragma unroll
    for (int i = 0; i < 16; ++i) {
        s[i] = sc[lane * 16 + i];
        uint32_t u = __float_as_uint(s[i]);
        key[i] = (u >> 31) ? ~u : (u | 0x80000000u);
    }
    uint32_t prefix = 0;
    for (int bit = 31; bit >= 0; --bit) {
        uint32_t cand = prefix | (1u << bit);
        int c = 0;
        #pragma unroll
        for (int i = 0; i < 16; ++i) c += (key[i] >= cand);
        #pragma unroll
        for (int off = 1; off < 64; off <<= 1) c += __shfl_xor(c, off);
        if (c >= 256) prefix = cand;
    }
    int cg = 0, eq = 0;
    #pragma unroll
    for (int i = 0; i < 16; ++i) { cg += (key[i] > prefix); eq += (key[i] == prefix); }
    #pragma unroll
    for (int off = 1; off < 64; off <<= 1) cg += __shfl_xor(cg, off);
    const int quota = 256 - cg;
    int xs = eq;
    #pragma unroll
    for (int off = 1; off < 64; off <<= 1) {
        int y = __shfl_up(xs, off);
        if (lane >= off) xs += y;
    }
    int run = xs - eq;
    bool selv[16];
    int cnt = 0;
    #pragma unroll
    for (int i = 0; i < 16; ++i) {
        bool sel = key[i] > prefix;
        if (key[i] == prefix) { sel = (run < quota); run++; }
        selv[i] = sel;
        cnt += sel ? 1 : 0;
        gate[w * 1024 + lane * 16 + i] = sel ? 1.0f / (1.0f + expf(-s[i])) : 0.0f;
    }
    int xc = cnt;
    #pragma unroll
    for (int off = 1; off < 64; off <<= 1) {
        int y = __shfl_up(xc, off);
        if (lane >= off) xc += y;
    }
    int pos = xc - cnt;
    #pragma unroll
    for (int i = 0; i < 16; ++i) {
        if (selv[i]) {
            idx[w * 256 + pos]  = lane * 16 + i;
            gsel[w * 256 + pos] = 1.0f / (1.0f + expf(-s[i]));
            pos++;
        }
    }
}

// ---------------------------------------------------------------------------
// K3: gathered QKV GEMM, M=1152 (1024 selected + 8 xsum-hi/lo + 120 pad),
// N=3072 (q|k|v). (unchanged)
// ---------------------------------------------------------------------------
__global__ __launch_bounds__(256) void k_qkv_sel(
    const bf16* __restrict__ xb, const bf16* __restrict__ wqb,
    const int* __restrict__ idx, const bf16* __restrict__ xsumhl,
    bf16* __restrict__ qsel, bf16* __restrict__ ksel,
    bf16* __restrict__ vsel, float* __restrict__ SumVparts) {
    __shared__ bf16 As[128 * 32];
    __shared__ bf16 Bs[128 * 32];
    const int t = threadIdx.x;
    const int lane = t & 63;
    const int w = t >> 6;
    const int n0 = blockIdx.x * 128;   // 0..2944
    const int m0 = blockIdx.y * 128;   // 0..1024
    const bf16* Bsrc = wqb + (size_t)n0 * 1024;

    const int srow = t >> 2;
    const int scol = (t & 3) * 8;
    const int wm = (w & 1) * 64;
    const int wn = (w >> 1) * 64;
    const int fr = lane & 15;
    const int kc = (lane >> 4) * 8;

    const int mg1 = m0 + srow, mg2 = mg1 + 64;
    const bf16* ap1;
    const bf16* ap2;
    if (mg1 < 1024)
        ap1 = xb + ((size_t)(mg1 >> 8) * 1024 + idx[(mg1 >> 8) * 256 + (mg1 & 255)]) * 1024;
    else if (mg1 < 1032) ap1 = xsumhl + (size_t)(mg1 - 1024) * 1024;
    else ap1 = xb;
    if (mg2 < 1024)
        ap2 = xb + ((size_t)(mg2 >> 8) * 1024 + idx[(mg2 >> 8) * 256 + (mg2 & 255)]) * 1024;
    else if (mg2 < 1032) ap2 = xsumhl + (size_t)(mg2 - 1024) * 1024;
    else ap2 = xb;

    floatx4 zero4 = {0.f, 0.f, 0.f, 0.f};
    floatx4 acc[4][4];
    #pragma unroll
    for (int i = 0; i < 4; ++i)
        #pragma unroll
        for (int j = 0; j < 4; ++j) acc[i][j] = zero4;

    for (int k0 = 0; k0 < 1024; k0 += 32) {
        __syncthreads();
        cp16(As + t * 8,        ap1 + k0 + scol);
        cp16(As + t * 8 + 2048, ap2 + k0 + scol);
        cp16(Bs + t * 8,        Bsrc + (size_t)srow * 1024 + k0 + scol);
        cp16(Bs + t * 8 + 2048, Bsrc + (size_t)(srow + 64) * 1024 + k0 + scol);
        __syncthreads();
        bf16x8 a[4], b[4];
        #pragma unroll
        for (int mi = 0; mi < 4; ++mi)
            a[mi] = *(const bf16x8*)&As[(wm + mi * 16 + fr) * 32 + kc];
        #pragma unroll
        for (int ni = 0; ni < 4; ++ni)
            b[ni] = *(const bf16x8*)&Bs[(wn + ni * 16 + fr) * 32 + kc];
        #pragma unroll
        for (int mi = 0; mi < 4; ++mi)
            #pragma unroll
            for (int ni = 0; ni < 4; ++ni)
                acc[mi][ni] = MFMA16(a[mi], b[ni], acc[mi][ni]);
    }

    const int rowb = (lane >> 4) * 4;
    #pragma unroll
    for (int ni = 0; ni < 4; ++ni) {
        const int n_base = n0 + wn + ni * 16;
        const int region = n_base >> 10;   // 0=q 1=k 2=v
        const int nn = n_base & 1023;
        const int h = nn >> 6;
        const int dd = (nn & 63) + fr;
        #pragma unroll
        for (int mi = 0; mi < 4; ++mi) {
            #pragma unroll
            for (int r = 0; r < 4; ++r) {
                const int mg = m0 + wm + mi * 16 + rowb + r;
                const float av = acc[mi][ni][r];
                if (mg < 1024) {
                    const int b = mg >> 8, s = mg & 255;
                    const bf16 v = (bf16)av;
                    if (region == 0)
                        qsel[(size_t)mg * 1024 + h * 64 + dd] = v;
                    else if (region == 1)
                        ksel[(((size_t)(b * 16 + h)) * 256 + s) * 64 + dd] = v;
                    else
                        vsel[(((size_t)(b * 16 + h)) * 256 + s) * 64 + dd] = v;
                } else if (mg < 1032 && region == 2) {
                    SumVparts[(size_t)(mg - 1024) * 1024 + h * 64 + dd] = av;
                }
            }
        }
    }
}

// ---------------------------------------------------------------------------
// K3b: per-bh transpose vsel -> VselT, SumVsel, SumVuns, meanV row (unchanged).
// ---------------------------------------------------------------------------
__global__ __launch_bounds__(256) void k_vgather(
    const bf16* __restrict__ vsel, const float* __restrict__ SumVparts,
    bf16* __restrict__ VselT, float* __restrict__ SumVuns,
    bf16* __restrict__ qsel) {
    const int bh = blockIdx.x, b = bh >> 4, h = bh & 15;
    const int t = threadIdx.x;
    const bf16* vb = vsel + (size_t)bh * 16384;
    bf16* Vo = VselT + (size_t)bh * 16384;

    __shared__ bf16 Vt[64][72];
    __shared__ float redSel[4][64];

    const int d = t & 63, sg = t >> 6;
    const int s_loc = t >> 2, part = t & 3;
    float sSel = 0.f;

    for (int c = 0; c < 4; ++c) {
        __syncthreads();
        const uint4* vsrc = (const uint4*)(vb + (size_t)(c * 64 + s_loc) * 64 + part * 16);
        uint4 v0 = vsrc[0], v1 = vsrc[1];
        *(uint4*)&Vt[s_loc][part * 16]     = v0;
        *(uint4*)&Vt[s_loc][part * 16 + 8] = v1;
        __syncthreads();
        union { bf16 h_[16]; uint4 u[2]; } tmp;
        #pragma unroll
        for (int u = 0; u < 16; ++u) {
            bf16 v = Vt[sg * 16 + u][d];
            tmp.h_[u] = v;
            sSel += (float)v;
        }
        uint4* vdst = (uint4*)(Vo + (size_t)d * 256 + c * 64 + sg * 16);
        vdst[0] = tmp.u[0]; vdst[1] = tmp.u[1];
    }
    redSel[sg][d] = sSel;
    __syncthreads();
    if (t < 64) {
        float sa = SumVparts[(size_t)b * 1024 + h * 64 + t] +
                   SumVparts[(size_t)(4 + b) * 1024 + h * 64 + t];
        float ss = redSel[0][t] + redSel[1][t] + redSel[2][t] + redSel[3][t];
        SumVuns[bh * 64 + t] = sa - ss;
        qsel[(size_t)(1024 + b) * 1024 + h * 64 + t] = (bf16)(sa * (1.f / 1024.f));
    }
}

// ---------------------------------------------------------------------------
// K4: gated attention (unchanged).
// ---------------------------------------------------------------------------
__global__ __launch_bounds__(256) void k_attn(
    bf16* __restrict__ qsel, const bf16* __restrict__ Ksel,
    const bf16* __restrict__ VselT, const float* __restrict__ gsel,
    const float* __restrict__ SumVuns) {
    const int bh = blockIdx.x;   // 0..63
    const int qt = blockIdx.y;   // 0..3
    const int b = bh >> 4, h = bh & 15;
    const int t = threadIdx.x, w = t >> 6, lane = t & 63;
    const int m0 = qt * 64;
    const bf16* kb = Ksel + (size_t)bh * 16384;
    const bf16* vb = VselT + (size_t)bh * 16384;

    __shared__ bf16 Qs[64 * 72];
    __shared__ bf16 Ks[64 * 72];
    __shared__ bf16 Vs[64 * 72];
    __shared__ bf16 Ps[4][16 * 72];

    #pragma unroll
    for (int c = 0; c < 2; ++c) {
        int idx2 = t + 256 * c, row = idx2 >> 3, c8 = (idx2 & 7) * 8;
        *(uint4*)&Qs[row * 72 + c8] =
            *(const uint4*)&qsel[(size_t)(b * 256 + m0 + row) * 1024 + h * 64 + c8];
    }
    const int fr = lane & 15;
    const int kq = lane >> 4;
    const int rowb = kq * 4;
    __syncthreads();
    bf16x8 aq[2];
    aq[0] = *(const bf16x8*)&Qs[(w * 16 + fr) * 72 + kq * 8];
    aq[1] = *(const bf16x8*)&Qs[(w * 16 + fr) * 72 + 32 + kq * 8];

    float gq[4];
    #pragma unroll
    for (int r = 0; r < 4; ++r)
        gq[r] = gsel[b * 256 + m0 + w * 16 + rowb + r] * SCALE_;

    float mrow[4] = {0.f, 0.f, 0.f, 0.f};
    float lrow[4] = {0.f, 0.f, 0.f, 0.f};
    floatx4 zero4 = {0.f, 0.f, 0.f, 0.f};
    floatx4 Of[4] = {zero4, zero4, zero4, zero4};

    for (int jt = 0; jt < 4; ++jt) {
        const int j0 = jt * 64;
        __syncthreads();
        #pragma unroll
        for (int c = 0; c < 2; ++c) {
            int idx2 = t + 256 * c, row = idx2 >> 3, c8 = (idx2 & 7) * 8;
            *(uint4*)&Ks[row * 72 + c8] = *(const uint4*)&kb[(size_t)(j0 + row) * 64 + c8];
            *(uint4*)&Vs[row * 72 + c8] = *(const uint4*)&vb[(size_t)row * 256 + j0 + c8];
        }
        __syncthreads();

        floatx4 S[4] = {zero4, zero4, zero4, zero4};
        #pragma unroll
        for (int ks = 0; ks < 2; ++ks) {
            #pragma unroll
            for (int ni = 0; ni < 4; ++ni) {
                bf16x8 bfr = *(const bf16x8*)&Ks[(ni * 16 + fr) * 72 + ks * 32 + kq * 8];
                S[ni] = MFMA16(aq[ks], bfr, S[ni]);
            }
        }
        float gk[4];
        #pragma unroll
        for (int ni = 0; ni < 4; ++ni) gk[ni] = gsel[b * 256 + j0 + ni * 16 + fr];

        float p[4][4], rmax[4] = {0.f, 0.f, 0.f, 0.f};
        #pragma unroll
        for (int ni = 0; ni < 4; ++ni)
            #pragma unroll
            for (int r = 0; r < 4; ++r) {
                float sv = S[ni][r] * (gq[r] * gk[ni]);
                p[ni][r] = sv;
                rmax[r] = fmaxf(rmax[r], sv);
            }
        #pragma unroll
        for (int r = 0; r < 4; ++r) {
            #pragma unroll
            for (int off = 1; off < 16; off <<= 1)
                rmax[r] = fmaxf(rmax[r], __shfl_xor(rmax[r], off));
        }
        float alpha[4], rsum[4] = {0.f, 0.f, 0.f, 0.f};
        #pragma unroll
        for (int r = 0; r < 4; ++r) {
            float mn = fmaxf(mrow[r], rmax[r]);
            alpha[r] = __expf(mrow[r] - mn);
            mrow[r] = mn;
        }
        #pragma unroll
        for (int ni = 0; ni < 4; ++ni)
            #pragma unroll
            for (int r = 0; r < 4; ++r) {
                float pv = __expf(p[ni][r] - mrow[r]);
                p[ni][r] = pv;
                rsum[r] += pv;
            }
        #pragma unroll
        for (int r = 0; r < 4; ++r) {
            #pragma unroll
            for (int off = 1; off < 16; off <<= 1) rsum[r] += __shfl_xor(rsum[r], off);
            lrow[r] = lrow[r] * alpha[r] + rsum[r];
        }
        #pragma unroll
        for (int nd = 0; nd < 4; ++nd)
            #pragma unroll
            for (int r = 0; r < 4; ++r) Of[nd][r] *= alpha[r];

        #pragma unroll
        for (int ni = 0; ni < 4; ++ni)
            #pragma unroll
            for (int r = 0; r < 4; ++r)
                Ps[w][(rowb + r) * 72 + ni * 16 + fr] = (bf16)p[ni][r];

        #pragma unroll
        for (int ks = 0; ks < 2; ++ks) {
            bf16x8 ap = *(const bf16x8*)&Ps[w][fr * 72 + ks * 32 + kq * 8];
            #pragma unroll
            for (int nd = 0; nd < 4; ++nd) {
                bf16x8 bv = *(const bf16x8*)&Vs[(nd * 16 + fr) * 72 + ks * 32 + kq * 8];
                Of[nd] = MFMA16(ap, bv, Of[nd]);
            }
        }
    }

    #pragma unroll
    for (int nd = 0; nd < 4; ++nd)
        #pragma unroll
        for (int r = 0; r < 4; ++r) {
            float em = __expf(-mrow[r]);
            float num = Of[nd][r] + em * SumVuns[bh * 64 + nd * 16 + fr];
            float den = lrow[r] + 768.0f * em;
            qsel[(size_t)(b * 256 + m0 + w * 16 + rowb + r) * 1024 +
                 h * 64 + nd * 16 + fr] = (bf16)(num / den);
        }
}

// ---------------------------------------------------------------------------
// K5: out GEMM on compact A (unchanged).
// ---------------------------------------------------------------------------
__global__ __launch_bounds__(256) void k_out_sel(
    const bf16* __restrict__ A, const bf16* __restrict__ wob,
    const float* __restrict__ b_out, const int* __restrict__ idx,
    float* __restrict__ ubase, float* __restrict__ out) {
    __shared__ bf16 As[128 * 32];
    __shared__ bf16 Bs[128 * 32];
    const int t = threadIdx.x;
    const int lane = t & 63;
    const int w = t >> 6;
    const int n0 = blockIdx.x * 128;
    const int m0 = blockIdx.y * 128;
    const bf16* Bsrc = wob + (size_t)n0 * 1024;

    const int srow = t >> 2;
    const int scol = (t & 3) * 8;
    const int wm = (w & 1) * 64;
    const int wn = (w >> 1) * 64;
    const int fr = lane & 15;
    const int kc = (lane >> 4) * 8;

    floatx4 zero4 = {0.f, 0.f, 0.f, 0.f};
    floatx4 acc[4][4];
    #pragma unroll
    for (int i = 0; i < 4; ++i)
        #pragma unroll
        for (int j = 0; j < 4; ++j) acc[i][j] = zero4;

    for (int k0 = 0; k0 < 1024; k0 += 32) {
        __syncthreads();
        cp16(As + t * 8,        A + (size_t)(m0 + srow) * 1024 + k0 + scol);
        cp16(As + t * 8 + 2048, A + (size_t)(m0 + srow + 64) * 1024 + k0 + scol);
        cp16(Bs + t * 8,        Bsrc + (size_t)srow * 1024 + k0 + scol);
        cp16(Bs + t * 8 + 2048, Bsrc + (size_t)(srow + 64) * 1024 + k0 + scol);
        __syncthreads();
        bf16x8 a[4], b[4];
        #pragma unroll
        for (int mi = 0; mi < 4; ++mi)
            a[mi] = *(const bf16x8*)&As[(wm + mi * 16 + fr) * 32 + kc];
        #pragma unroll
        for (int ni = 0; ni < 4; ++ni)
            b[ni] = *(const bf16x8*)&Bs[(wn + ni * 16 + fr) * 32 + kc];
        #pragma unroll
        for (int mi = 0; mi < 4; ++mi)
            #pragma unroll
            for (int ni = 0; ni < 4; ++ni)
                acc[mi][ni] = MFMA16(a[mi], b[ni], acc[mi][ni]);
    }

    const int rowb = (lane >> 4) * 4;
    #pragma unroll
    for (int ni = 0; ni < 4; ++ni) {
        const int ng = n0 + wn + ni * 16 + fr;
        const float bias = b_out[ng];
        #pragma unroll
        for (int mi = 0; mi < 4; ++mi)
            #pragma unroll
            for (int r = 0; r < 4; ++r) {
                const int mg = m0 + wm + mi * 16 + rowb + r;
                const float val = acc[mi][ni][r] + bias;
                if (mg < 1024) {
                    const int b = mg >> 8, s = mg & 255;
                    const int tok = idx[b * 256 + s];
                    out[((size_t)b * 1024 + tok) * 1024 + ng] = val;
                } else if (mg < 1028) {
                    ubase[(size_t)(mg - 1024) * 1024 + ng] = val;
                }
            }
    }
}

// ---------------------------------------------------------------------------
// K6: broadcast ubase[b] to all unselected token rows (unchanged).
// ---------------------------------------------------------------------------
__global__ __launch_bounds__(256) void k_fill(
    const float* __restrict__ gate, const float* __restrict__ ubase,
    float* __restrict__ out) {
    const int tokg = blockIdx.x;   // 0..4095
    if (gate[tokg] > 0.f) return;
    const int b = tokg >> 10;
    const int c = threadIdx.x * 4;
    *(float4*)(out + (size_t)tokg * 1024 + c) = *(const float4*)(ubase + b * 1024 + c);
}

// ---------------------------------------------------------------------------
extern "C" void kernel_launch(void* const* d_in, const int* in_sizes, int n_in,
                              void* d_out, int out_size, void* d_ws, size_t ws_size,
                              hipStream_t stream) {
    const float* x     = (const float*)d_in[0];
    const float* w_qkv = (const float*)d_in[1];
    const float* w_out = (const float*)d_in[2];
    const float* b_out = (const float*)d_in[3];
    const float* ln_g  = (const float*)d_in[4];
    const float* ln_b  = (const float*)d_in[5];
    const float* w1    = (const float*)d_in[6];
    const float* b1    = (const float*)d_in[7];
    const float* w2    = (const float*)d_in[8];
    const float* b2    = (const float*)d_in[9];
    float* out = (float*)d_out;

    char* ws = (char*)d_ws;
    bf16*  qsel  = (bf16*)(ws);                  // 4 MB slot (1152x1024 bf16)
    bf16*  ksel  = (bf16*)(ws + 4194304);        // 2 MB
    bf16*  VselT = (bf16*)(ws + 6291456);        // 2 MB
    bf16*  vsel  = (bf16*)(ws + 8388608);        // 2 MB
    float* partial   = (float*)(ws + 10485760);  // 256 KB (xsum stage A)
    float* SumVparts = (float*)(ws + 10747904);  // 32 KB
    bf16*  xsumhl    = (bf16*)(ws + 10780672);   // 16 KB (8x1024 bf16)
    bf16*  xb    = (bf16*)(ws + 16777216);       // 8 MB
    bf16*  wqb   = (bf16*)(ws + 25165824);       // 6 MB
    bf16*  wob   = (bf16*)(ws + 31457280);       // 2 MB
    int*   idx     = (int*)(ws + 33554432);      // 4 KB
    float* gsel    = (float*)(ws + 33558528);    // 4 KB
    float* scores  = (float*)(ws + 33562624);    // 16 KB
    float* gate    = (float*)(ws + 33579008);    // 16 KB
    float* SumVuns = (float*)(ws + 33595392);    // 16 KB
    float* ubase   = (float*)(ws + 33611776);    // 16 KB
    bf16*  whl     = (bf16*)(ws + 33685504);     // 256 KB (wh|wl rows)
    bf16*  xlbuf   = (bf16*)(ws + 35651584);     // 8 MB (x bf16 residual)

    k_cvt_prep<<<4416, 256, 0, stream>>>(x, w_qkv, w_out, xb, xlbuf, wqb, wob,
                                         whl, partial);
    k_score_gemm<<<48, 256, 0, stream>>>(xb, xlbuf, whl, partial, xsumhl,
                                         ln_g, ln_b, w1, b1, w2, b2, scores);
    k_topk<<<1, 256, 0, stream>>>(scores, gate, idx, gsel);
    k_qkv_sel<<<dim3(24, 9), 256, 0, stream>>>(xb, wqb, idx, xsumhl, qsel, ksel,
                                               vsel, SumVparts);
    k_vgather<<<64, 256, 0, stream>>>(vsel, SumVparts, VselT, SumVuns, qsel);
    k_attn<<<dim3(64, 4), 256, 0, stream>>>(qsel, ksel, VselT, gsel, SumVuns);
    k_out_sel<<<dim3(8, 9), 256, 0, stream>>>(qsel, wob, b_out, idx, ubase, out);
    k_fill<<<4096, 256, 0, stream>>>(gate, ubase, out);
}

// Round 12
// 228.558 us; speedup vs baseline: 1.1335x; 1.1335x over previous
//
#include <hip/hip_runtime.h>
#include <hip/hip_bf16.h>
#include <stdint.h>

typedef __bf16 bf16;
typedef __bf16 bf16x8 __attribute__((ext_vector_type(8)));
typedef float floatx4 __attribute__((ext_vector_type(4)));

typedef const __attribute__((address_space(1))) uint32_t glb_u32;
typedef __attribute__((address_space(3))) uint32_t lds_u32;

__device__ __forceinline__ void cp16(void* lds, const void* gp) {
    __builtin_amdgcn_global_load_lds((glb_u32*)gp, (lds_u32*)lds, 16, 0, 0);
}

#define MFMA16(a, b, c) __builtin_amdgcn_mfma_f32_16x16x32_bf16((a), (b), (c), 0, 0, 0)
#define SCALE_ 0.125f

// ---------------------------------------------------------------------------
// K0: fused cvt + prep (round-8 proven configuration).
// blocks [0,4096): fp32->bf16 cvt of x (hi + lo residual), w_qkv, w_out
// blocks [4096,4352): whl[d][k]=bf16_hi(mean_h wq), whl[64+d][k]=bf16_lo
// ---------------------------------------------------------------------------
__global__ __launch_bounds__(256) void k_cvt_prep(
    const float* __restrict__ x, const float* __restrict__ wq,
    const float* __restrict__ wo, bf16* __restrict__ xb,
    bf16* __restrict__ xl, bf16* __restrict__ wqb, bf16* __restrict__ wob,
    bf16* __restrict__ whl) {
    if (blockIdx.x < 4096) {
        size_t i8 = ((size_t)blockIdx.x * 256 + threadIdx.x) * 8;
        const float* src; bf16* dst; size_t off; bool isx = false;
        if (i8 < 4194304)      { src = x;  dst = xb;  off = i8; isx = true; }
        else if (i8 < 7340032) { src = wq; dst = wqb; off = i8 - 4194304; }
        else                   { src = wo; dst = wob; off = i8 - 7340032; }
        float4 a = *(const float4*)(src + off);
        float4 b = *(const float4*)(src + off + 4);
        union { bf16 h[8]; uint4 u; } hi, lo;
        hi.h[0] = (bf16)a.x; hi.h[1] = (bf16)a.y; hi.h[2] = (bf16)a.z; hi.h[3] = (bf16)a.w;
        hi.h[4] = (bf16)b.x; hi.h[5] = (bf16)b.y; hi.h[6] = (bf16)b.z; hi.h[7] = (bf16)b.w;
        *(uint4*)(dst + off) = hi.u;
        if (isx) {
            lo.h[0] = (bf16)(a.x - (float)hi.h[0]);
            lo.h[1] = (bf16)(a.y - (float)hi.h[1]);
            lo.h[2] = (bf16)(a.z - (float)hi.h[2]);
            lo.h[3] = (bf16)(a.w - (float)hi.h[3]);
            lo.h[4] = (bf16)(b.x - (float)hi.h[4]);
            lo.h[5] = (bf16)(b.y - (float)hi.h[5]);
            lo.h[6] = (bf16)(b.z - (float)hi.h[6]);
            lo.h[7] = (bf16)(b.w - (float)hi.h[7]);
            *(uint4*)(xl + off) = lo.u;
        }
    } else {
        int t = (blockIdx.x - 4096) * 256 + threadIdx.x;   // 0..65535
        int k = t & 1023, d = t >> 10;
        float s = 0.f;
        #pragma unroll
        for (int h = 0; h < 16; ++h) s += wq[(size_t)(h * 64 + d) * 1024 + k];
        s *= (1.f / 16.f);
        bf16 hi = (bf16)s;
        whl[(size_t)d * 1024 + k] = hi;
        whl[(size_t)(64 + d) * 1024 + k] = (bf16)(s - (float)hi);
    }
}

// ---------------------------------------------------------------------------
// K1a: qm GEMM via hi/lo-split MFMA: qm = xh·wh + xh·wl + xl·wh (fp32 acc).
// 32 blocks x 128 rows; wave owns 32-row stripe, N=64.
// ---------------------------------------------------------------------------
__global__ __launch_bounds__(256) void k_score_gemm(
    const bf16* __restrict__ xh, const bf16* __restrict__ xl,
    const bf16* __restrict__ whl, float* __restrict__ qmbuf) {
    __shared__ bf16 Ah[128 * 32];
    __shared__ bf16 Al[128 * 32];
    __shared__ bf16 Bs[128 * 32];
    const int t = threadIdx.x;
    const int lane = t & 63;
    const int w = t >> 6;
    const int m0 = blockIdx.x * 128;
    const int srow = t >> 2;
    const int scol = (t & 3) * 8;
    const int fr = lane & 15;
    const int kc = (lane >> 4) * 8;
    const int wm0 = w * 32;

    floatx4 zero4 = {0.f, 0.f, 0.f, 0.f};
    floatx4 acc[2][4];
    #pragma unroll
    for (int i = 0; i < 2; ++i)
        #pragma unroll
        for (int j = 0; j < 4; ++j) acc[i][j] = zero4;

    for (int k0 = 0; k0 < 1024; k0 += 32) {
        __syncthreads();
        cp16(Ah + t * 8,        xh + (size_t)(m0 + srow) * 1024 + k0 + scol);
        cp16(Ah + t * 8 + 2048, xh + (size_t)(m0 + srow + 64) * 1024 + k0 + scol);
        cp16(Al + t * 8,        xl + (size_t)(m0 + srow) * 1024 + k0 + scol);
        cp16(Al + t * 8 + 2048, xl + (size_t)(m0 + srow + 64) * 1024 + k0 + scol);
        cp16(Bs + t * 8,        whl + (size_t)srow * 1024 + k0 + scol);
        cp16(Bs + t * 8 + 2048, whl + (size_t)(srow + 64) * 1024 + k0 + scol);
        __syncthreads();
        bf16x8 ah[2], al[2], bh[4], bl[4];
        #pragma unroll
        for (int mi = 0; mi < 2; ++mi) {
            ah[mi] = *(const bf16x8*)&Ah[(wm0 + mi * 16 + fr) * 32 + kc];
            al[mi] = *(const bf16x8*)&Al[(wm0 + mi * 16 + fr) * 32 + kc];
        }
        #pragma unroll
        for (int ni = 0; ni < 4; ++ni) {
            bh[ni] = *(const bf16x8*)&Bs[(ni * 16 + fr) * 32 + kc];
            bl[ni] = *(const bf16x8*)&Bs[(64 + ni * 16 + fr) * 32 + kc];
        }
        #pragma unroll
        for (int mi = 0; mi < 2; ++mi)
            #pragma unroll
            for (int ni = 0; ni < 4; ++ni) {
                acc[mi][ni] = MFMA16(ah[mi], bh[ni], acc[mi][ni]);
                acc[mi][ni] = MFMA16(ah[mi], bl[ni], acc[mi][ni]);
                acc[mi][ni] = MFMA16(al[mi], bh[ni], acc[mi][ni]);
            }
    }

    const int rowb = (lane >> 4) * 4;
    #pragma unroll
    for (int mi = 0; mi < 2; ++mi)
        #pragma unroll
        for (int ni = 0; ni < 4; ++ni)
            #pragma unroll
            for (int r = 0; r < 4; ++r) {
                const int row = m0 + wm0 + mi * 16 + rowb + r;
                qmbuf[(size_t)row * 64 + ni * 16 + fr] = acc[mi][ni][r];
            }
}

// ---------------------------------------------------------------------------
// K1b: LN -> GELU -> score from qmbuf. Wave = 1 row.
// ---------------------------------------------------------------------------
__global__ __launch_bounds__(256) void k_score_tail(
    const float* __restrict__ qmbuf, const float* __restrict__ lng,
    const float* __restrict__ lnb, const float* __restrict__ w1f,
    const float* __restrict__ b1f, const float* __restrict__ w2f,
    const float* __restrict__ b2f, float* __restrict__ scores) {
    const int w = threadIdx.x >> 6, lane = threadIdx.x & 63;
    const int r = blockIdx.x * 4 + w;
    __shared__ float Hs[4][64];
    __shared__ float hh[4][16];

    float qm = qmbuf[(size_t)r * 64 + lane];
    float s = qm;
    #pragma unroll
    for (int off = 32; off > 0; off >>= 1) s += __shfl_xor(s, off);
    float mu = s * (1.f / 64.f);
    float dx = qm - mu;
    float v2 = dx * dx;
    #pragma unroll
    for (int off = 32; off > 0; off >>= 1) v2 += __shfl_xor(v2, off);
    float var = v2 * (1.f / 64.f);
    float H = dx * (1.0f / sqrtf(var + 1e-5f)) * lng[lane] + lnb[lane];
    Hs[w][lane] = H;
    if (lane < 16) {
        float a = b1f[lane];
        #pragma unroll
        for (int d = 0; d < 64; ++d) a += Hs[w][d] * w1f[lane * 64 + d];
        hh[w][lane] = 0.5f * a * (1.0f + erff(a * 0.70710678118654752f));
    }
    if (lane == 0) {
        float sc = b2f[0];
        #pragma unroll
        for (int p = 0; p < 16; ++p) sc += hh[w][p] * w2f[p];
        scores[r] = sc;
    }
}

// ---------------------------------------------------------------------------
// K2: top-256 radix select; emits full gate, ascending index list, compact gate.
// ---------------------------------------------------------------------------
__global__ __launch_bounds__(256) void k_topk(const float* __restrict__ scores,
                                              float* __restrict__ gate,
                                              int* __restrict__ idx,
                                              float* __restrict__ gsel) {
    const int w = threadIdx.x >> 6, lane = threadIdx.x & 63;   // w = batch
    const float* sc = scores + w * 1024;
    float s[16];
    uint32_t key[16];
    #pragma unroll
    for (int i = 0; i < 16; ++i) {
        s[i] = sc[lane * 16 + i];
        uint32_t u = __float_as_uint(s[i]);
        key[i] = (u >> 31) ? ~u : (u | 0x80000000u);
    }
    uint32_t prefix = 0;
    for (int bit = 31; bit >= 0; --bit) {
        uint32_t cand = prefix | (1u << bit);
        int c = 0;
        #pragma unroll
        for (int i = 0; i < 16; ++i) c += (key[i] >= cand);
        #pragma unroll
        for (int off = 1; off < 64; off <<= 1) c += __shfl_xor(c, off);
        if (c >= 256) prefix = cand;
    }
    int cg = 0, eq = 0;
    #pragma unroll
    for (int i = 0; i < 16; ++i) { cg += (key[i] > prefix); eq += (key[i] == prefix); }
    #pragma unroll
    for (int off = 1; off < 64; off <<= 1) cg += __shfl_xor(cg, off);
    const int quota = 256 - cg;
    int xs = eq;
    #pragma unroll
    for (int off = 1; off < 64; off <<= 1) {
        int y = __shfl_up(xs, off);
        if (lane >= off) xs += y;
    }
    int run = xs - eq;
    bool selv[16];
    int cnt = 0;
    #pragma unroll
    for (int i = 0; i < 16; ++i) {
        bool sel = key[i] > prefix;
        if (key[i] == prefix) { sel = (run < quota); run++; }
        selv[i] = sel;
        cnt += sel ? 1 : 0;
        gate[w * 1024 + lane * 16 + i] = sel ? 1.0f / (1.0f + expf(-s[i])) : 0.0f;
    }
    int xc = cnt;
    #pragma unroll
    for (int off = 1; off < 64; off <<= 1) {
        int y = __shfl_up(xc, off);
        if (lane >= off) xc += y;
    }
    int pos = xc - cnt;
    #pragma unroll
    for (int i = 0; i < 16; ++i) {
        if (selv[i]) {
            idx[w * 256 + pos]  = lane * 16 + i;
            gsel[w * 256 + pos] = 1.0f / (1.0f + expf(-s[i]));
            pos++;
        }
    }
}

// ---------------------------------------------------------------------------
// K3: sparse QKV. blocks [0,256): V = x @ wv^T for ALL tokens -> vbuf[bh][n][d]
//     blocks [256,384): Q,K for the 1024 gathered (selected) rows ->
//       qsel[compact 1024][1024] (cols h*64+d), ksel[bh][256][64]
// ---------------------------------------------------------------------------
__global__ __launch_bounds__(256) void k_qkv_sel(
    const bf16* __restrict__ xb, const bf16* __restrict__ wqb,
    const int* __restrict__ idx, bf16* __restrict__ qsel,
    bf16* __restrict__ ksel, bf16* __restrict__ vbuf) {
    __shared__ bf16 As[128 * 32];
    __shared__ bf16 Bs[128 * 32];
    const int t = threadIdx.x;
    const int lane = t & 63;
    const int w = t >> 6;
    const int srow = t >> 2;
    const int scol = (t & 3) * 8;
    const int wm = (w & 1) * 64;
    const int wn = (w >> 1) * 64;
    const int fr = lane & 15;
    const int kc = (lane >> 4) * 8;

    const int bid = blockIdx.x;
    const bool isV = bid < 256;
    int n0, m0;
    size_t abase1, abase2;
    const bf16* Bsrc;
    if (isV) {
        n0 = (bid & 7) * 128;          // V col space [0,1024)
        m0 = (bid >> 3) * 128;         // token rows [0,4096)
        Bsrc = wqb + (size_t)(2048 + n0) * 1024;
        abase1 = (size_t)(m0 + srow) * 1024;
        abase2 = (size_t)(m0 + srow + 64) * 1024;
    } else {
        int q = bid - 256;
        n0 = (q & 15) * 128;           // [0,2048) over wq|wk
        m0 = (q >> 4) * 128;           // compact rows [0,1024)
        Bsrc = wqb + (size_t)n0 * 1024;
        const int mg1 = m0 + srow, mg2 = mg1 + 64;
        const int tok1 = idx[(mg1 >> 8) * 256 + (mg1 & 255)];
        const int tok2 = idx[(mg2 >> 8) * 256 + (mg2 & 255)];
        abase1 = ((size_t)(mg1 >> 8) * 1024 + tok1) * 1024;
        abase2 = ((size_t)(mg2 >> 8) * 1024 + tok2) * 1024;
    }

    floatx4 zero4 = {0.f, 0.f, 0.f, 0.f};
    floatx4 acc[4][4];
    #pragma unroll
    for (int i = 0; i < 4; ++i)
        #pragma unroll
        for (int j = 0; j < 4; ++j) acc[i][j] = zero4;

    for (int k0 = 0; k0 < 1024; k0 += 32) {
        __syncthreads();
        cp16(As + t * 8,        xb + abase1 + k0 + scol);
        cp16(As + t * 8 + 2048, xb + abase2 + k0 + scol);
        cp16(Bs + t * 8,        Bsrc + (size_t)srow * 1024 + k0 + scol);
        cp16(Bs + t * 8 + 2048, Bsrc + (size_t)(srow + 64) * 1024 + k0 + scol);
        __syncthreads();
        bf16x8 a[4], b[4];
        #pragma unroll
        for (int mi = 0; mi < 4; ++mi)
            a[mi] = *(const bf16x8*)&As[(wm + mi * 16 + fr) * 32 + kc];
        #pragma unroll
        for (int ni = 0; ni < 4; ++ni)
            b[ni] = *(const bf16x8*)&Bs[(wn + ni * 16 + fr) * 32 + kc];
        #pragma unroll
        for (int mi = 0; mi < 4; ++mi)
            #pragma unroll
            for (int ni = 0; ni < 4; ++ni)
                acc[mi][ni] = MFMA16(a[mi], b[ni], acc[mi][ni]);
    }

    const int rowb = (lane >> 4) * 4;
    #pragma unroll
    for (int ni = 0; ni < 4; ++ni) {
        const int n_base = n0 + wn + ni * 16;
        if (isV) {
            const int h = n_base >> 6;
            const int dd = (n_base & 63) + fr;
            #pragma unroll
            for (int mi = 0; mi < 4; ++mi)
                #pragma unroll
                for (int r = 0; r < 4; ++r) {
                    const int mg = m0 + wm + mi * 16 + rowb + r;
                    const int bb = mg >> 10, nq = mg & 1023;
                    vbuf[(((size_t)(bb * 16 + h)) * 1024 + nq) * 64 + dd] =
                        (bf16)acc[mi][ni][r];
                }
        } else {
            const int region = n_base >> 10;   // 0=q 1=k
            const int nn = n_base & 1023;
            const int h = nn >> 6;
            const int dd = (nn & 63) + fr;
            #pragma unroll
            for (int mi = 0; mi < 4; ++mi)
                #pragma unroll
                for (int r = 0; r < 4; ++r) {
                    const int mg = m0 + wm + mi * 16 + rowb + r;  // compact row
                    const bf16 v = (bf16)acc[mi][ni][r];
                    if (region == 0) {
                        qsel[(size_t)mg * 1024 + h * 64 + dd] = v;
                    } else {
                        const int b = mg >> 8, s = mg & 255;
                        ksel[(((size_t)(b * 16 + h)) * 256 + s) * 64 + dd] = v;
                    }
                }
        }
    }
}

// ---------------------------------------------------------------------------
// K3b: per-bh: VselT[bh][64][256] gather+transpose, SumVuns[bh][64],
//      meanV row -> qsel row (1024+b), cols h*64..h*64+63.
// ---------------------------------------------------------------------------
__global__ __launch_bounds__(256) void k_vgather(
    const bf16* __restrict__ vbuf, const int* __restrict__ idx,
    bf16* __restrict__ VselT, float* __restrict__ SumVuns,
    bf16* __restrict__ qsel) {
    const int bh = blockIdx.x, b = bh >> 4, h = bh & 15;
    const int t = threadIdx.x, w = t >> 6, lane = t & 63;
    const bf16* vb = vbuf + (size_t)bh * 65536;
    bf16* Vo = VselT + (size_t)bh * 16384;

    __shared__ bf16 Vt[64][72];
    __shared__ float redAll[4][64];
    __shared__ float redSel[4][64];

    float sAll = 0.f;
    for (int j = w * 256; j < w * 256 + 256; ++j)
        sAll += (float)vb[(size_t)j * 64 + lane];
    redAll[w][lane] = sAll;

    const int d = t & 63, sg = t >> 6;
    const int s_loc = t >> 2, part = t & 3;
    float sSel = 0.f;

    for (int c = 0; c < 4; ++c) {
        __syncthreads();
        int j = idx[b * 256 + c * 64 + s_loc];
        const uint4* vsrc = (const uint4*)(vb + (size_t)j * 64 + part * 16);
        uint4 v0 = vsrc[0], v1 = vsrc[1];
        *(uint4*)&Vt[s_loc][part * 16]     = v0;
        *(uint4*)&Vt[s_loc][part * 16 + 8] = v1;
        __syncthreads();
        union { bf16 h_[16]; uint4 u[2]; } tmp;
        #pragma unroll
        for (int u = 0; u < 16; ++u) {
            bf16 v = Vt[sg * 16 + u][d];
            tmp.h_[u] = v;
            sSel += (float)v;
        }
        uint4* vdst = (uint4*)(Vo + (size_t)d * 256 + c * 64 + sg * 16);
        vdst[0] = tmp.u[0]; vdst[1] = tmp.u[1];
    }
    redSel[sg][d] = sSel;
    __syncthreads();
    if (t < 64) {
        float sa = redAll[0][t] + redAll[1][t] + redAll[2][t] + redAll[3][t];
        float ss = redSel[0][t] + redSel[1][t] + redSel[2][t] + redSel[3][t];
        SumVuns[bh * 64 + t] = sa - ss;
        qsel[(size_t)(1024 + b) * 1024 + h * 64 + t] = (bf16)(sa * (1.f / 1024.f));
    }
}

// ---------------------------------------------------------------------------
// K4: gated attention over 256 selected rows x 256 selected cols per bh,
// + closed-form correction for the 768 zero-score cols. In-place over qsel.
// ---------------------------------------------------------------------------
__global__ __launch_bounds__(256) void k_attn(
    bf16* __restrict__ qsel, const bf16* __restrict__ Ksel,
    const bf16* __restrict__ VselT, const float* __restrict__ gsel,
    const float* __restrict__ SumVuns) {
    const int bh = blockIdx.x;   // 0..63
    const int qt = blockIdx.y;   // 0..3
    const int b = bh >> 4, h = bh & 15;
    const int t = threadIdx.x, w = t >> 6, lane = t & 63;
    const int m0 = qt * 64;      // compact row within batch
    const bf16* kb = Ksel + (size_t)bh * 16384;
    const bf16* vb = VselT + (size_t)bh * 16384;

    __shared__ bf16 Qs[64 * 72];
    __shared__ bf16 Ks[64 * 72];
    __shared__ bf16 Vs[64 * 72];
    __shared__ bf16 Ps[4][16 * 72];

    #pragma unroll
    for (int c = 0; c < 2; ++c) {
        int idx2 = t + 256 * c, row = idx2 >> 3, c8 = (idx2 & 7) * 8;
        *(uint4*)&Qs[row * 72 + c8] =
            *(const uint4*)&qsel[(size_t)(b * 256 + m0 + row) * 1024 + h * 64 + c8];
    }
    const int fr = lane & 15;
    const int kq = lane >> 4;
    const int rowb = kq * 4;
    __syncthreads();
    bf16x8 aq[2];
    aq[0] = *(const bf16x8*)&Qs[(w * 16 + fr) * 72 + kq * 8];
    aq[1] = *(const bf16x8*)&Qs[(w * 16 + fr) * 72 + 32 + kq * 8];

    float gq[4];
    #pragma unroll
    for (int r = 0; r < 4; ++r)
        gq[r] = gsel[b * 256 + m0 + w * 16 + rowb + r] * SCALE_;

    float mrow[4] = {0.f, 0.f, 0.f, 0.f};
    float lrow[4] = {0.f, 0.f, 0.f, 0.f};
    floatx4 zero4 = {0.f, 0.f, 0.f, 0.f};
    floatx4 Of[4] = {zero4, zero4, zero4, zero4};

    for (int jt = 0; jt < 4; ++jt) {
        const int j0 = jt * 64;
        __syncthreads();
        #pragma unroll
        for (int c = 0; c < 2; ++c) {
            int idx2 = t + 256 * c, row = idx2 >> 3, c8 = (idx2 & 7) * 8;
            *(uint4*)&Ks[row * 72 + c8] = *(const uint4*)&kb[(size_t)(j0 + row) * 64 + c8];
            *(uint4*)&Vs[row * 72 + c8] = *(const uint4*)&vb[(size_t)row * 256 + j0 + c8];
        }
        __syncthreads();

        floatx4 S[4] = {zero4, zero4, zero4, zero4};
        #pragma unroll
        for (int ks = 0; ks < 2; ++ks) {
            #pragma unroll
            for (int ni = 0; ni < 4; ++ni) {
                bf16x8 bfr = *(const bf16x8*)&Ks[(ni * 16 + fr) * 72 + ks * 32 + kq * 8];
                S[ni] = MFMA16(aq[ks], bfr, S[ni]);
            }
        }
        float gk[4];
        #pragma unroll
        for (int ni = 0; ni < 4; ++ni) gk[ni] = gsel[b * 256 + j0 + ni * 16 + fr];

        float p[4][4], rmax[4] = {0.f, 0.f, 0.f, 0.f};
        #pragma unroll
        for (int ni = 0; ni < 4; ++ni)
            #pragma unroll
            for (int r = 0; r < 4; ++r) {
                float sv = S[ni][r] * (gq[r] * gk[ni]);
                p[ni][r] = sv;
                rmax[r] = fmaxf(rmax[r], sv);
            }
        #pragma unroll
        for (int r = 0; r < 4; ++r) {
            #pragma unroll
            for (int off = 1; off < 16; off <<= 1)
                rmax[r] = fmaxf(rmax[r], __shfl_xor(rmax[r], off));
        }
        float alpha[4], rsum[4] = {0.f, 0.f, 0.f, 0.f};
        #pragma unroll
        for (int r = 0; r < 4; ++r) {
            float mn = fmaxf(mrow[r], rmax[r]);
            alpha[r] = __expf(mrow[r] - mn);
            mrow[r] = mn;
        }
        #pragma unroll
        for (int ni = 0; ni < 4; ++ni)
            #pragma unroll
            for (int r = 0; r < 4; ++r) {
                float pv = __expf(p[ni][r] - mrow[r]);
                p[ni][r] = pv;
                rsum[r] += pv;
            }
        #pragma unroll
        for (int r = 0; r < 4; ++r) {
            #pragma unroll
            for (int off = 1; off < 16; off <<= 1) rsum[r] += __shfl_xor(rsum[r], off);
            lrow[r] = lrow[r] * alpha[r] + rsum[r];
        }
        #pragma unroll
        for (int nd = 0; nd < 4; ++nd)
            #pragma unroll
            for (int r = 0; r < 4; ++r) Of[nd][r] *= alpha[r];

        #pragma unroll
        for (int ni = 0; ni < 4; ++ni)
            #pragma unroll
            for (int r = 0; r < 4; ++r)
                Ps[w][(rowb + r) * 72 + ni * 16 + fr] = (bf16)p[ni][r];

        #pragma unroll
        for (int ks = 0; ks < 2; ++ks) {
            bf16x8 ap = *(const bf16x8*)&Ps[w][fr * 72 + ks * 32 + kq * 8];
            #pragma unroll
            for (int nd = 0; nd < 4; ++nd) {
                bf16x8 bv = *(const bf16x8*)&Vs[(nd * 16 + fr) * 72 + ks * 32 + kq * 8];
                Of[nd] = MFMA16(ap, bv, Of[nd]);
            }
        }
    }

    #pragma unroll
    for (int nd = 0; nd < 4; ++nd)
        #pragma unroll
        for (int r = 0; r < 4; ++r) {
            float em = __expf(-mrow[r]);
            float num = Of[nd][r] + em * SumVuns[bh * 64 + nd * 16 + fr];
            float den = lrow[r] + 768.0f * em;
            qsel[(size_t)(b * 256 + m0 + w * 16 + rowb + r) * 1024 +
                 h * 64 + nd * 16 + fr] = (bf16)(num / den);
        }
}

// ---------------------------------------------------------------------------
// K5: out GEMM on compact A (1152 rows: 1024 selected + 4 meanV + 124 pad).
// Selected rows scatter to d_out; meanV rows -> ubase; pad discarded.
// ---------------------------------------------------------------------------
__global__ __launch_bounds__(256) void k_out_sel(
    const bf16* __restrict__ A, const bf16* __restrict__ wob,
    const float* __restrict__ b_out, const int* __restrict__ idx,
    float* __restrict__ ubase, float* __restrict__ out) {
    __shared__ bf16 As[128 * 32];
    __shared__ bf16 Bs[128 * 32];
    const int t = threadIdx.x;
    const int lane = t & 63;
    const int w = t >> 6;
    const int n0 = blockIdx.x * 128;
    const int m0 = blockIdx.y * 128;
    const bf16* Bsrc = wob + (size_t)n0 * 1024;

    const int srow = t >> 2;
    const int scol = (t & 3) * 8;
    const int wm = (w & 1) * 64;
    const int wn = (w >> 1) * 64;
    const int fr = lane & 15;
    const int kc = (lane >> 4) * 8;

    floatx4 zero4 = {0.f, 0.f, 0.f, 0.f};
    floatx4 acc[4][4];
    #pragma unroll
    for (int i = 0; i < 4; ++i)
        #pragma unroll
        for (int j = 0; j < 4; ++j) acc[i][j] = zero4;

    for (int k0 = 0; k0 < 1024; k0 += 32) {
        __syncthreads();
        cp16(As + t * 8,        A + (size_t)(m0 + srow) * 1024 + k0 + scol);
        cp16(As + t * 8 + 2048, A + (size_t)(m0 + srow + 64) * 1024 + k0 + scol);
        cp16(Bs + t * 8,        Bsrc + (size_t)srow * 1024 + k0 + scol);
        cp16(Bs + t * 8 + 2048, Bsrc + (size_t)(srow + 64) * 1024 + k0 + scol);
        __syncthreads();
        bf16x8 a[4], b[4];
        #pragma unroll
        for (int mi = 0; mi < 4; ++mi)
            a[mi] = *(const bf16x8*)&As[(wm + mi * 16 + fr) * 32 + kc];
        #pragma unroll
        for (int ni = 0; ni < 4; ++ni)
            b[ni] = *(const bf16x8*)&Bs[(wn + ni * 16 + fr) * 32 + kc];
        #pragma unroll
        for (int mi = 0; mi < 4; ++mi)
            #pragma unroll
            for (int ni = 0; ni < 4; ++ni)
                acc[mi][ni] = MFMA16(a[mi], b[ni], acc[mi][ni]);
    }

    const int rowb = (lane >> 4) * 4;
    #pragma unroll
    for (int ni = 0; ni < 4; ++ni) {
        const int ng = n0 + wn + ni * 16 + fr;
        const float bias = b_out[ng];
        #pragma unroll
        for (int mi = 0; mi < 4; ++mi)
            #pragma unroll
            for (int r = 0; r < 4; ++r) {
                const int mg = m0 + wm + mi * 16 + rowb + r;
                const float val = acc[mi][ni][r] + bias;
                if (mg < 1024) {
                    const int b = mg >> 8, s = mg & 255;
                    const int tok = idx[b * 256 + s];
                    out[((size_t)b * 1024 + tok) * 1024 + ng] = val;
                } else if (mg < 1028) {
                    ubase[(size_t)(mg - 1024) * 1024 + ng] = val;
                }
            }
    }
}

// ---------------------------------------------------------------------------
// K6: broadcast ubase[b] to all unselected token rows.
// ---------------------------------------------------------------------------
__global__ __launch_bounds__(256) void k_fill(
    const float* __restrict__ gate, const float* __restrict__ ubase,
    float* __restrict__ out) {
    const int tokg = blockIdx.x;   // 0..4095
    if (gate[tokg] > 0.f) return;
    const int b = tokg >> 10;
    const int c = threadIdx.x * 4;
    *(float4*)(out + (size_t)tokg * 1024 + c) = *(const float4*)(ubase + b * 1024 + c);
}

// ---------------------------------------------------------------------------
extern "C" void kernel_launch(void* const* d_in, const int* in_sizes, int n_in,
                              void* d_out, int out_size, void* d_ws, size_t ws_size,
                              hipStream_t stream) {
    const float* x     = (const float*)d_in[0];
    const float* w_qkv = (const float*)d_in[1];
    const float* w_out = (const float*)d_in[2];
    const float* b_out = (const float*)d_in[3];
    const float* ln_g  = (const float*)d_in[4];
    const float* ln_b  = (const float*)d_in[5];
    const float* w1    = (const float*)d_in[6];
    const float* b1    = (const float*)d_in[7];
    const float* w2    = (const float*)d_in[8];
    const float* b2    = (const float*)d_in[9];
    float* out = (float*)d_out;

    char* ws = (char*)d_ws;
    bf16*  qsel  = (bf16*)(ws);                  // 4 MB slot (1152x1024 bf16)
    bf16*  ksel  = (bf16*)(ws + 4194304);        // 2 MB
    bf16*  VselT = (bf16*)(ws + 6291456);        // 2 MB
    bf16*  vbuf  = (bf16*)(ws + 8388608);        // 8 MB
    bf16*  xb    = (bf16*)(ws + 16777216);       // 8 MB
    bf16*  wqb   = (bf16*)(ws + 25165824);       // 6 MB
    bf16*  wob   = (bf16*)(ws + 31457280);       // 2 MB
    int*   idx     = (int*)(ws + 33554432);      // 4 KB
    float* gsel    = (float*)(ws + 33558528);    // 4 KB
    float* scores  = (float*)(ws + 33562624);    // 16 KB
    float* gate    = (float*)(ws + 33579008);    // 16 KB
    float* SumVuns = (float*)(ws + 33595392);    // 16 KB
    float* ubase   = (float*)(ws + 33611776);    // 16 KB
    bf16*  whl     = (bf16*)(ws + 33685504);     // 256 KB (wh|wl rows)
    float* qmbuf   = (float*)(ws + 34603008);    // 1 MB
    bf16*  xlbuf   = (bf16*)(ws + 35651584);     // 8 MB (x bf16 residual)

    k_cvt_prep<<<4352, 256, 0, stream>>>(x, w_qkv, w_out, xb, xlbuf, wqb, wob, whl);
    k_score_gemm<<<32, 256, 0, stream>>>(xb, xlbuf, whl, qmbuf);
    k_score_tail<<<1024, 256, 0, stream>>>(qmbuf, ln_g, ln_b, w1, b1, w2, b2, scores);
    k_topk<<<1, 256, 0, stream>>>(scores, gate, idx, gsel);
    k_qkv_sel<<<384, 256, 0, stream>>>(xb, wqb, idx, qsel, ksel, vbuf);
    k_vgather<<<64, 256, 0, stream>>>(vbuf, idx, VselT, SumVuns, qsel);
    k_attn<<<dim3(64, 4), 256, 0, stream>>>(qsel, ksel, VselT, gsel, SumVuns);
    k_out_sel<<<dim3(8, 9), 256, 0, stream>>>(qsel, wob, b_out, idx, ubase, out);
    k_fill<<<4096, 256, 0, stream>>>(gate, ubase, out);
}